// Round 1
// baseline (530.342 us; speedup 1.0000x reference)
//
#include <hip/hip_runtime.h>
#include <cmath>

#define B_ 4
#define T_ 2048
#define C_ 1024
#define H_ 64
#define SCALE_ 0.03125f   /* 1024^-0.5 */

// ---------------- projection: q,k,v = x @ {Wq,Wk,Wv} ----------------
// 32 rows/block, 256 threads. Thread t: col = t&63 (same col in all 3 W),
// rowgroup g = t>>6 (8 rows each). x tile staged transposed in LDS.
__global__ __launch_bounds__(256) void proj_kernel(
    const float* __restrict__ x, const float* __restrict__ Wq,
    const float* __restrict__ Wk, const float* __restrict__ Wv,
    float* __restrict__ q, float* __restrict__ k, float* __restrict__ v)
{
    __shared__ float xs[64][36];   // [kk][row], pad 36 keeps 16B alignment of 8-row groups
    const int t = threadIdx.x;
    const int col = t & 63;
    const int r0 = (t >> 6) * 8;
    const int row0 = blockIdx.x * 32;

    float aq[8] = {0,0,0,0,0,0,0,0};
    float ak[8] = {0,0,0,0,0,0,0,0};
    float av[8] = {0,0,0,0,0,0,0,0};

    for (int kt = 0; kt < C_; kt += 64) {
        __syncthreads();
        for (int i = t; i < 32 * 64; i += 256) {
            int r = i >> 6, kk = i & 63;
            xs[kk][r] = x[(size_t)(row0 + r) * C_ + kt + kk];
        }
        __syncthreads();
        #pragma unroll 4
        for (int kk = 0; kk < 64; ++kk) {
            float wq = Wq[(size_t)(kt + kk) * H_ + col];
            float wk = Wk[(size_t)(kt + kk) * H_ + col];
            float wv = Wv[(size_t)(kt + kk) * H_ + col];
            const float* xr = &xs[kk][r0];   // wave-uniform -> broadcast reads
            #pragma unroll
            for (int r = 0; r < 8; ++r) {
                float xv = xr[r];
                aq[r] = fmaf(xv, wq, aq[r]);
                ak[r] = fmaf(xv, wk, ak[r]);
                av[r] = fmaf(xv, wv, av[r]);
            }
        }
    }
    #pragma unroll
    for (int r = 0; r < 8; ++r) {
        size_t o = (size_t)(row0 + r0 + r) * H_ + col;
        q[o] = aq[r]; k[o] = ak[r]; v[o] = av[r];
    }
}

// ---------------- causal flash attention ----------------
// Block: 4 waves x 4 query rows = 16 rows. Grid: B * T/16 = 512.
// K tile XOR-swizzled float4 chunks for conflict-free per-lane b128 reads.
__global__ __launch_bounds__(256) void attn_kernel(
    const float* __restrict__ q, const float* __restrict__ k,
    const float* __restrict__ v, float* __restrict__ out)
{
    __shared__ float4 Ks4[64][16];     // [key][chunk ^ (key&15)]
    __shared__ float4 Vs4[64][16];     // [key][chunk] linear
    __shared__ float4 qs4[16][16];     // [row][chunk]
    __shared__ float4 ps4[4][4][16];   // [wave][row][chunk]

    const int t = threadIdx.x;
    const int lane = t & 63;
    const int w = t >> 6;
    const int blk = blockIdx.x;
    const int b = blk >> 7;
    const int qbase = (127 - (blk & 127)) << 4;   // reversed: big workloads dispatch first
    const size_t base = (size_t)b * T_ * H_;

    // stage q tile (16 rows x 64) once
    {
        int row = t >> 4, c = t & 15;
        qs4[row][c] = *(const float4*)(q + base + (size_t)(qbase + row) * H_ + c * 4);
    }

    const int myrow0 = qbase + w * 4;
    float m[4], l[4], acc[4];
    #pragma unroll
    for (int r = 0; r < 4; ++r) { m[r] = -3.0e38f; l[r] = 0.f; acc[r] = 0.f; }

    const int ntiles = (qbase + 15) / 64 + 1;
    for (int kt = 0; kt < ntiles; ++kt) {
        const int kt0 = kt * 64;
        __syncthreads();
        #pragma unroll
        for (int i = t; i < 64 * 16; i += 256) {
            int key = i >> 4, c = i & 15;
            size_t g = base + (size_t)(kt0 + key) * H_ + c * 4;
            Ks4[key][c ^ (key & 15)] = *(const float4*)(k + g);
            Vs4[key][c]              = *(const float4*)(v + g);
        }
        __syncthreads();
        if (kt0 > myrow0 + 3) continue;   // this wave done; still hits next-loop barrier

        // ---- scores: lane = key, 4 query rows ----
        float s0 = 0.f, s1 = 0.f, s2 = 0.f, s3 = 0.f;
        const int swz = lane & 15;
        #pragma unroll
        for (int c = 0; c < 16; ++c) {
            float4 kk4 = Ks4[lane][c ^ swz];
            float4 q0 = qs4[w * 4 + 0][c];
            float4 q1 = qs4[w * 4 + 1][c];
            float4 q2 = qs4[w * 4 + 2][c];
            float4 q3 = qs4[w * 4 + 3][c];
            s0 = fmaf(kk4.x, q0.x, fmaf(kk4.y, q0.y, fmaf(kk4.z, q0.z, fmaf(kk4.w, q0.w, s0))));
            s1 = fmaf(kk4.x, q1.x, fmaf(kk4.y, q1.y, fmaf(kk4.z, q1.z, fmaf(kk4.w, q1.w, s1))));
            s2 = fmaf(kk4.x, q2.x, fmaf(kk4.y, q2.y, fmaf(kk4.z, q2.z, fmaf(kk4.w, q2.w, s2))));
            s3 = fmaf(kk4.x, q3.x, fmaf(kk4.y, q3.y, fmaf(kk4.z, q3.z, fmaf(kk4.w, q3.w, s3))));
        }
        float s[4] = {s0, s1, s2, s3};

        // ---- online softmax per row ----
        #pragma unroll
        for (int r = 0; r < 4; ++r) {
            const int qrow = myrow0 + r;
            float sc = (kt0 + lane <= qrow) ? s[r] * SCALE_ : -3.0e38f;
            float mx = sc;
            #pragma unroll
            for (int d = 1; d < 64; d <<= 1) mx = fmaxf(mx, __shfl_xor(mx, d));
            float mn = fmaxf(m[r], mx);
            float p = __expf(sc - mn);          // masked lanes underflow to 0
            float corr = __expf(m[r] - mn);
            m[r] = mn;
            float psum = p;
            #pragma unroll
            for (int d = 1; d < 64; d <<= 1) psum += __shfl_xor(psum, d);
            l[r] = l[r] * corr + psum;
            acc[r] *= corr;
            ((float*)&ps4[w][r])[lane] = p;
        }

        // ---- PV: lane = h column ----
        const float* Vsf = (const float*)Vs4;
        #pragma unroll
        for (int kc = 0; kc < 16; ++kc) {
            float4 p0 = ps4[w][0][kc];
            float4 p1 = ps4[w][1][kc];
            float4 p2 = ps4[w][2][kc];
            float4 p3 = ps4[w][3][kc];
            float vv;
            vv = Vsf[(kc * 4 + 0) * 64 + lane];
            acc[0] = fmaf(p0.x, vv, acc[0]); acc[1] = fmaf(p1.x, vv, acc[1]);
            acc[2] = fmaf(p2.x, vv, acc[2]); acc[3] = fmaf(p3.x, vv, acc[3]);
            vv = Vsf[(kc * 4 + 1) * 64 + lane];
            acc[0] = fmaf(p0.y, vv, acc[0]); acc[1] = fmaf(p1.y, vv, acc[1]);
            acc[2] = fmaf(p2.y, vv, acc[2]); acc[3] = fmaf(p3.y, vv, acc[3]);
            vv = Vsf[(kc * 4 + 2) * 64 + lane];
            acc[0] = fmaf(p0.z, vv, acc[0]); acc[1] = fmaf(p1.z, vv, acc[1]);
            acc[2] = fmaf(p2.z, vv, acc[2]); acc[3] = fmaf(p3.z, vv, acc[3]);
            vv = Vsf[(kc * 4 + 3) * 64 + lane];
            acc[0] = fmaf(p0.w, vv, acc[0]); acc[1] = fmaf(p1.w, vv, acc[1]);
            acc[2] = fmaf(p2.w, vv, acc[2]); acc[3] = fmaf(p3.w, vv, acc[3]);
        }
    }

    #pragma unroll
    for (int r = 0; r < 4; ++r)
        out[base + (size_t)(myrow0 + r) * H_ + lane] = acc[r] / l[r];
}

extern "C" void kernel_launch(void* const* d_in, const int* in_sizes, int n_in,
                              void* d_out, int out_size, void* d_ws, size_t ws_size,
                              hipStream_t stream) {
    const float* x  = (const float*)d_in[0];
    const float* Wq = (const float*)d_in[1];
    const float* Wk = (const float*)d_in[2];
    const float* Wv = (const float*)d_in[3];
    float* outp = (float*)d_out;

    const size_t n = (size_t)B_ * T_ * H_;   // 524288
    float* qw = (float*)d_ws;
    float* kw = qw + n;
    float* vw = kw + n;

    proj_kernel<<<(B_ * T_) / 32, 256, 0, stream>>>(x, Wq, Wk, Wv, qw, kw, vw);
    attn_kernel<<<B_ * (T_ / 16), 256, 0, stream>>>(qw, kw, vw, outp);
}

// Round 2
// 200.172 us; speedup vs baseline: 2.6494x; 2.6494x over previous
//
#include <hip/hip_runtime.h>
#include <cmath>

#define B_ 4
#define T_ 2048
#define C_ 1024
#define H_ 64
#define SCALE_ 0.03125f   /* 1024^-0.5 */

typedef __attribute__((ext_vector_type(4))) float f32x4;
typedef __attribute__((ext_vector_type(8))) short s16x8;
typedef __attribute__((ext_vector_type(4))) unsigned short u16x4;

__device__ inline unsigned short f2bf(float f) {
    union { float f; unsigned u; } v; v.f = f;
    unsigned r = v.u + 0x7FFFu + ((v.u >> 16) & 1u);
    return (unsigned short)(r >> 16);
}

#define LDK 72  /* padded k-stride in bf16 elems: even bank spread on b128 reads */

// ---------------- projection via bf16 MFMA ----------------
// Grid: 128 row-tiles x 3 matrices = 384 blocks. Block: 64 rows x 64 cols,
// 4 waves in 2x2 -> wave tile 32x32 = 2x2 mfma_f32_16x16x32_bf16 frags.
// f32->bf16 conversion fused into LDS staging. Output q/k/v stay f32.
__global__ __launch_bounds__(256) void proj_mfma(
    const float* __restrict__ x, const float* __restrict__ Wq,
    const float* __restrict__ Wk, const float* __restrict__ Wv,
    float* __restrict__ q, float* __restrict__ k, float* __restrict__ v)
{
    __shared__ unsigned short As[64 * LDK];   // [row][k]
    __shared__ unsigned short Bs[64 * LDK];   // [col][k]  (W transposed)

    const int t = threadIdx.x;
    const int lane = t & 63;
    const int w = t >> 6;
    const int blk = blockIdx.x;
    const int mat = blk % 3;
    const int row0 = (blk / 3) * 64;

    const float* W = (mat == 0) ? Wq : (mat == 1) ? Wk : Wv;
    float* outp = (mat == 0) ? q : (mat == 1) ? k : v;

    const int wr = (w >> 1) * 32;   // wave row offset in block tile
    const int wc = (w & 1) * 32;    // wave col offset
    const int fr = lane & 15;
    const int ko = (lane >> 4) * 8;

    f32x4 acc[2][2];
    #pragma unroll
    for (int mi = 0; mi < 2; ++mi)
        #pragma unroll
        for (int ni = 0; ni < 2; ++ni)
            acc[mi][ni] = (f32x4){0.f, 0.f, 0.f, 0.f};

    const int bcol = t & 63;          // B-staging: this thread's W column
    const int bkg  = (t >> 6) * 4;    // and k-group base

    for (int kt = 0; kt < C_; kt += 64) {
        __syncthreads();
        // stage A: x tile 64x64 f32 -> bf16. 16 lanes cover 256B/row: coalesced.
        #pragma unroll
        for (int i = 0; i < 4; ++i) {
            int idx = t + i * 256;
            int r = idx >> 4, kc = (idx & 15) * 4;
            f32x4 xv = *(const f32x4*)(x + (size_t)(row0 + r) * C_ + kt + kc);
            u16x4 bv;
            bv.x = f2bf(xv.x); bv.y = f2bf(xv.y); bv.z = f2bf(xv.z); bv.w = f2bf(xv.w);
            *(u16x4*)&As[r * LDK + kc] = bv;
        }
        // stage B transposed: 4 strided (coalesced 256B) W loads -> b64 store
        #pragma unroll
        for (int i = 0; i < 4; ++i) {
            int kk0 = bkg + i * 16;
            u16x4 bv;
            bv.x = f2bf(W[(size_t)(kt + kk0 + 0) * H_ + bcol]);
            bv.y = f2bf(W[(size_t)(kt + kk0 + 1) * H_ + bcol]);
            bv.z = f2bf(W[(size_t)(kt + kk0 + 2) * H_ + bcol]);
            bv.w = f2bf(W[(size_t)(kt + kk0 + 3) * H_ + bcol]);
            *(u16x4*)&Bs[bcol * LDK + kk0] = bv;
        }
        __syncthreads();
        #pragma unroll
        for (int ks = 0; ks < 2; ++ks) {
            s16x8 a0 = *(const s16x8*)&As[(wr + fr) * LDK + ks * 32 + ko];
            s16x8 a1 = *(const s16x8*)&As[(wr + 16 + fr) * LDK + ks * 32 + ko];
            s16x8 b0 = *(const s16x8*)&Bs[(wc + fr) * LDK + ks * 32 + ko];
            s16x8 b1 = *(const s16x8*)&Bs[(wc + 16 + fr) * LDK + ks * 32 + ko];
            acc[0][0] = __builtin_amdgcn_mfma_f32_16x16x32_bf16(a0, b0, acc[0][0], 0, 0, 0);
            acc[0][1] = __builtin_amdgcn_mfma_f32_16x16x32_bf16(a0, b1, acc[0][1], 0, 0, 0);
            acc[1][0] = __builtin_amdgcn_mfma_f32_16x16x32_bf16(a1, b0, acc[1][0], 0, 0, 0);
            acc[1][1] = __builtin_amdgcn_mfma_f32_16x16x32_bf16(a1, b1, acc[1][1], 0, 0, 0);
        }
    }

    // C/D layout (m89-verified): col = lane&15, row = (lane>>4)*4 + reg
    #pragma unroll
    for (int mi = 0; mi < 2; ++mi)
        #pragma unroll
        for (int ni = 0; ni < 2; ++ni)
            #pragma unroll
            for (int j = 0; j < 4; ++j) {
                int row = row0 + wr + mi * 16 + (lane >> 4) * 4 + j;
                int col = wc + ni * 16 + fr;
                outp[(size_t)row * H_ + col] = acc[mi][ni][j];
            }
}

// ---------------- causal flash attention (unchanged from R1) ----------------
__global__ __launch_bounds__(256) void attn_kernel(
    const float* __restrict__ q, const float* __restrict__ k,
    const float* __restrict__ v, float* __restrict__ out)
{
    __shared__ float4 Ks4[64][16];     // [key][chunk ^ (key&15)]
    __shared__ float4 Vs4[64][16];     // [key][chunk] linear
    __shared__ float4 qs4[16][16];     // [row][chunk]
    __shared__ float4 ps4[4][4][16];   // [wave][row][chunk]

    const int t = threadIdx.x;
    const int lane = t & 63;
    const int w = t >> 6;
    const int blk = blockIdx.x;
    const int b = blk >> 7;
    const int qbase = (127 - (blk & 127)) << 4;   // reversed: big workloads dispatch first
    const size_t base = (size_t)b * T_ * H_;

    // stage q tile (16 rows x 64) once
    {
        int row = t >> 4, c = t & 15;
        qs4[row][c] = *(const float4*)(q + base + (size_t)(qbase + row) * H_ + c * 4);
    }

    const int myrow0 = qbase + w * 4;
    float m[4], l[4], acc[4];
    #pragma unroll
    for (int r = 0; r < 4; ++r) { m[r] = -3.0e38f; l[r] = 0.f; acc[r] = 0.f; }

    const int ntiles = (qbase + 15) / 64 + 1;
    for (int kt = 0; kt < ntiles; ++kt) {
        const int kt0 = kt * 64;
        __syncthreads();
        #pragma unroll
        for (int i = t; i < 64 * 16; i += 256) {
            int key = i >> 4, c = i & 15;
            size_t g = base + (size_t)(kt0 + key) * H_ + c * 4;
            Ks4[key][c ^ (key & 15)] = *(const float4*)(k + g);
            Vs4[key][c]              = *(const float4*)(v + g);
        }
        __syncthreads();
        if (kt0 > myrow0 + 3) continue;   // this wave done; still hits next-loop barrier

        // ---- scores: lane = key, 4 query rows ----
        float s0 = 0.f, s1 = 0.f, s2 = 0.f, s3 = 0.f;
        const int swz = lane & 15;
        #pragma unroll
        for (int c = 0; c < 16; ++c) {
            float4 kk4 = Ks4[lane][c ^ swz];
            float4 q0 = qs4[w * 4 + 0][c];
            float4 q1 = qs4[w * 4 + 1][c];
            float4 q2 = qs4[w * 4 + 2][c];
            float4 q3 = qs4[w * 4 + 3][c];
            s0 = fmaf(kk4.x, q0.x, fmaf(kk4.y, q0.y, fmaf(kk4.z, q0.z, fmaf(kk4.w, q0.w, s0))));
            s1 = fmaf(kk4.x, q1.x, fmaf(kk4.y, q1.y, fmaf(kk4.z, q1.z, fmaf(kk4.w, q1.w, s1))));
            s2 = fmaf(kk4.x, q2.x, fmaf(kk4.y, q2.y, fmaf(kk4.z, q2.z, fmaf(kk4.w, q2.w, s2))));
            s3 = fmaf(kk4.x, q3.x, fmaf(kk4.y, q3.y, fmaf(kk4.z, q3.z, fmaf(kk4.w, q3.w, s3))));
        }
        float s[4] = {s0, s1, s2, s3};

        // ---- online softmax per row ----
        #pragma unroll
        for (int r = 0; r < 4; ++r) {
            const int qrow = myrow0 + r;
            float sc = (kt0 + lane <= qrow) ? s[r] * SCALE_ : -3.0e38f;
            float mx = sc;
            #pragma unroll
            for (int d = 1; d < 64; d <<= 1) mx = fmaxf(mx, __shfl_xor(mx, d));
            float mn = fmaxf(m[r], mx);
            float p = __expf(sc - mn);          // masked lanes underflow to 0
            float corr = __expf(m[r] - mn);
            m[r] = mn;
            float psum = p;
            #pragma unroll
            for (int d = 1; d < 64; d <<= 1) psum += __shfl_xor(psum, d);
            l[r] = l[r] * corr + psum;
            acc[r] *= corr;
            ((float*)&ps4[w][r])[lane] = p;
        }

        // ---- PV: lane = h column ----
        const float* Vsf = (const float*)Vs4;
        #pragma unroll
        for (int kc = 0; kc < 16; ++kc) {
            float4 p0 = ps4[w][0][kc];
            float4 p1 = ps4[w][1][kc];
            float4 p2 = ps4[w][2][kc];
            float4 p3 = ps4[w][3][kc];
            float vv;
            vv = Vsf[(kc * 4 + 0) * 64 + lane];
            acc[0] = fmaf(p0.x, vv, acc[0]); acc[1] = fmaf(p1.x, vv, acc[1]);
            acc[2] = fmaf(p2.x, vv, acc[2]); acc[3] = fmaf(p3.x, vv, acc[3]);
            vv = Vsf[(kc * 4 + 1) * 64 + lane];
            acc[0] = fmaf(p0.y, vv, acc[0]); acc[1] = fmaf(p1.y, vv, acc[1]);
            acc[2] = fmaf(p2.y, vv, acc[2]); acc[3] = fmaf(p3.y, vv, acc[3]);
            vv = Vsf[(kc * 4 + 2) * 64 + lane];
            acc[0] = fmaf(p0.z, vv, acc[0]); acc[1] = fmaf(p1.z, vv, acc[1]);
            acc[2] = fmaf(p2.z, vv, acc[2]); acc[3] = fmaf(p3.z, vv, acc[3]);
            vv = Vsf[(kc * 4 + 3) * 64 + lane];
            acc[0] = fmaf(p0.w, vv, acc[0]); acc[1] = fmaf(p1.w, vv, acc[1]);
            acc[2] = fmaf(p2.w, vv, acc[2]); acc[3] = fmaf(p3.w, vv, acc[3]);
        }
    }

    #pragma unroll
    for (int r = 0; r < 4; ++r)
        out[base + (size_t)(myrow0 + r) * H_ + lane] = acc[r] / l[r];
}

extern "C" void kernel_launch(void* const* d_in, const int* in_sizes, int n_in,
                              void* d_out, int out_size, void* d_ws, size_t ws_size,
                              hipStream_t stream) {
    const float* x  = (const float*)d_in[0];
    const float* Wq = (const float*)d_in[1];
    const float* Wk = (const float*)d_in[2];
    const float* Wv = (const float*)d_in[3];
    float* outp = (float*)d_out;

    const size_t n = (size_t)B_ * T_ * H_;   // 524288
    float* qw = (float*)d_ws;
    float* kw = qw + n;
    float* vw = kw + n;

    proj_mfma<<<(B_ * T_ / 64) * 3, 256, 0, stream>>>(x, Wq, Wk, Wv, qw, kw, vw);
    attn_kernel<<<B_ * (T_ / 16), 256, 0, stream>>>(qw, kw, vw, outp);
}

// Round 3
// 50.091 us; speedup vs baseline: 10.5876x; 3.9962x over previous
//
#include <hip/hip_runtime.h>
#include <cmath>

#define B_ 4
#define T_ 2048
#define C_ 1024
#define H_ 64
#define SCALE_ 0.03125f   /* 1024^-0.5 */
#define NEG_ -3.0e38f

typedef __attribute__((ext_vector_type(4))) float f32x4;
typedef __attribute__((ext_vector_type(8))) short s16x8;
typedef __attribute__((ext_vector_type(4))) unsigned short u16x4;

__device__ inline unsigned short f2bf(float f) {
    union { float f; unsigned u; } v; v.f = f;
    unsigned r = v.u + 0x7FFFu + ((v.u >> 16) & 1u);
    return (unsigned short)(r >> 16);
}

#define LDK 72  /* padded k-stride in bf16 elems */

// ---------------- projection via bf16 MFMA ----------------
// Grid: 128 row-tiles x 3 matrices. Block 64x64, 4 waves 2x2.
// Outputs: qb,kb bf16 [8192][64]; vt bf16 [B][64][2048] (V transposed via LDS).
__global__ __launch_bounds__(256) void proj_mfma(
    const float* __restrict__ x, const float* __restrict__ Wq,
    const float* __restrict__ Wk, const float* __restrict__ Wv,
    unsigned short* __restrict__ qb, unsigned short* __restrict__ kb,
    unsigned short* __restrict__ vt)
{
    __shared__ unsigned short As[64 * LDK];   // [row][k]; reused as transpose buf
    __shared__ unsigned short Bs[64 * LDK];   // [col][k]  (W transposed)

    const int t = threadIdx.x;
    const int lane = t & 63;
    const int w = t >> 6;
    const int blk = blockIdx.x;
    const int mat = blk % 3;
    const int row0 = (blk / 3) * 64;

    const float* W = (mat == 0) ? Wq : (mat == 1) ? Wk : Wv;

    const int wr = (w >> 1) * 32;
    const int wc = (w & 1) * 32;
    const int fr = lane & 15;
    const int ko = (lane >> 4) * 8;

    f32x4 acc[2][2];
    #pragma unroll
    for (int mi = 0; mi < 2; ++mi)
        #pragma unroll
        for (int ni = 0; ni < 2; ++ni)
            acc[mi][ni] = (f32x4){0.f, 0.f, 0.f, 0.f};

    const int bcol = t & 63;
    const int bkg  = (t >> 6) * 4;

    for (int kt = 0; kt < C_; kt += 64) {
        __syncthreads();
        #pragma unroll
        for (int i = 0; i < 4; ++i) {
            int idx = t + i * 256;
            int r = idx >> 4, kc = (idx & 15) * 4;
            f32x4 xv = *(const f32x4*)(x + (size_t)(row0 + r) * C_ + kt + kc);
            u16x4 bv;
            bv.x = f2bf(xv.x); bv.y = f2bf(xv.y); bv.z = f2bf(xv.z); bv.w = f2bf(xv.w);
            *(u16x4*)&As[r * LDK + kc] = bv;
        }
        #pragma unroll
        for (int i = 0; i < 4; ++i) {
            int kk0 = bkg + i * 16;
            u16x4 bv;
            bv.x = f2bf(W[(size_t)(kt + kk0 + 0) * H_ + bcol]);
            bv.y = f2bf(W[(size_t)(kt + kk0 + 1) * H_ + bcol]);
            bv.z = f2bf(W[(size_t)(kt + kk0 + 2) * H_ + bcol]);
            bv.w = f2bf(W[(size_t)(kt + kk0 + 3) * H_ + bcol]);
            *(u16x4*)&Bs[bcol * LDK + kk0] = bv;
        }
        __syncthreads();
        #pragma unroll
        for (int ks = 0; ks < 2; ++ks) {
            s16x8 a0 = *(const s16x8*)&As[(wr + fr) * LDK + ks * 32 + ko];
            s16x8 a1 = *(const s16x8*)&As[(wr + 16 + fr) * LDK + ks * 32 + ko];
            s16x8 b0 = *(const s16x8*)&Bs[(wc + fr) * LDK + ks * 32 + ko];
            s16x8 b1 = *(const s16x8*)&Bs[(wc + 16 + fr) * LDK + ks * 32 + ko];
            acc[0][0] = __builtin_amdgcn_mfma_f32_16x16x32_bf16(a0, b0, acc[0][0], 0, 0, 0);
            acc[0][1] = __builtin_amdgcn_mfma_f32_16x16x32_bf16(a0, b1, acc[0][1], 0, 0, 0);
            acc[1][0] = __builtin_amdgcn_mfma_f32_16x16x32_bf16(a1, b0, acc[1][0], 0, 0, 0);
            acc[1][1] = __builtin_amdgcn_mfma_f32_16x16x32_bf16(a1, b1, acc[1][1], 0, 0, 0);
        }
    }

    // C/D layout: col = lane&15, row = (lane>>4)*4 + reg
    if (mat < 2) {
        unsigned short* outb = (mat == 0) ? qb : kb;
        #pragma unroll
        for (int mi = 0; mi < 2; ++mi)
            #pragma unroll
            for (int ni = 0; ni < 2; ++ni)
                #pragma unroll
                for (int j = 0; j < 4; ++j) {
                    int row = row0 + wr + mi * 16 + (lane >> 4) * 4 + j;
                    int col = wc + ni * 16 + fr;
                    outb[(size_t)row * H_ + col] = f2bf(acc[mi][ni][j]);
                }
    } else {
        // transpose V tile through LDS -> vt[b][h][t] coalesced
        __syncthreads();
        #pragma unroll
        for (int mi = 0; mi < 2; ++mi)
            #pragma unroll
            for (int ni = 0; ni < 2; ++ni)
                #pragma unroll
                for (int j = 0; j < 4; ++j) {
                    int r = wr + mi * 16 + (lane >> 4) * 4 + j;   // local key row
                    int cc = wc + ni * 16 + fr;                   // h
                    As[cc * LDK + r] = f2bf(acc[mi][ni][j]);
                }
        __syncthreads();
        int h = t >> 2, c0 = (t & 3) * 16;
        int bb = row0 >> 11, trow = row0 & 2047;
        s16x8 v0 = *(const s16x8*)&As[h * LDK + c0];
        s16x8 v1 = *(const s16x8*)&As[h * LDK + c0 + 8];
        size_t dst = (size_t)bb * H_ * T_ + (size_t)h * T_ + trow + c0;
        *(s16x8*)&vt[dst] = v0;
        *(s16x8*)&vt[dst + 8] = v1;
    }
}

// ---------------- MFMA flash attention, 8-way key-split ----------------
// Block: 512 thr = 8 waves; covers (batch, 16 q-rows). Wave s handles tile
// range [s*per, min(nt,(s+1)*per)) of 64-key tiles, keeps its own (m,l,O).
// No barriers in the K-loop: K/Vt B-frags straight from L2-resident global,
// P round-trips through per-wave swizzled LDS (same-wave DS is in-order).
__global__ __launch_bounds__(512, 4) void attn_mfma(
    const unsigned short* __restrict__ qb, const unsigned short* __restrict__ kb,
    const unsigned short* __restrict__ vt, float* __restrict__ out)
{
    __shared__ alignas(16) unsigned short Ps[8][1024];  // per-wave P (swizzled)
    __shared__ float Os[8][16][68];
    __shared__ float Mm[8][16];
    __shared__ float Ll[8][16];

    const int t = threadIdx.x, lane = t & 63, w = t >> 6;
    const int fr = lane & 15, hi4 = lane >> 4;
    const int blk = blockIdx.x;
    const int b = blk & 3;
    const int qt = 127 - (blk >> 2);     // big q-tiles dispatch first
    const int qbase = qt * 16;

    const unsigned short* qp = qb + ((size_t)b * T_ + qbase) * H_;
    const unsigned short* kp = kb + (size_t)b * T_ * H_;
    const unsigned short* vp = vt + (size_t)b * H_ * T_;

    // Q A-frags hoisted (rows = fr, k-chunks contiguous)
    s16x8 qf0 = *(const s16x8*)&qp[fr * H_ + hi4 * 8];
    s16x8 qf1 = *(const s16x8*)&qp[fr * H_ + 32 + hi4 * 8];

    const int nt = (qbase + 79) >> 6;    // tiles covering keys 0..qbase+15
    const int per = (nt + 7) >> 3;
    const int tb = w * per;
    int te = tb + per; if (te > nt) te = nt;

    float m[4], l[4];
    f32x4 o[4];
    #pragma unroll
    for (int j = 0; j < 4; ++j) { m[j] = NEG_; l[j] = 0.f; }
    #pragma unroll
    for (int hf = 0; hf < 4; ++hf) o[hf] = (f32x4){0.f, 0.f, 0.f, 0.f};

    unsigned short* P = &Ps[w][0];

    for (int kt = tb; kt < te; ++kt) {
        const int kt0 = kt << 6;

        // ---- QK^T: 4 key-frags x 2 k-steps ----
        f32x4 s[4];
        #pragma unroll
        for (int n = 0; n < 4; ++n) {
            const unsigned short* kr = &kp[(size_t)(kt0 + n * 16 + fr) * H_ + hi4 * 8];
            s16x8 kf0 = *(const s16x8*)kr;
            s16x8 kf1 = *(const s16x8*)(kr + 32);
            f32x4 a = (f32x4){0.f, 0.f, 0.f, 0.f};
            a = __builtin_amdgcn_mfma_f32_16x16x32_bf16(qf0, kf0, a, 0, 0, 0);
            a = __builtin_amdgcn_mfma_f32_16x16x32_bf16(qf1, kf1, a, 0, 0, 0);
            s[n] = a;
        }

        // ---- scale + causal mask (wave-uniform branch; kt0 <= qbase always) ----
        if (kt0 + 63 > qbase) {
            #pragma unroll
            for (int n = 0; n < 4; ++n)
                #pragma unroll
                for (int j = 0; j < 4; ++j) {
                    float sv = s[n][j] * SCALE_;
                    s[n][j] = (kt0 + n * 16 + fr > qbase + hi4 * 4 + j) ? NEG_ : sv;
                }
        } else {
            #pragma unroll
            for (int n = 0; n < 4; ++n)
                #pragma unroll
                for (int j = 0; j < 4; ++j) s[n][j] *= SCALE_;
        }

        // ---- online softmax in frag layout: 4-step 16-lane trees ----
        float mx[4];
        #pragma unroll
        for (int j = 0; j < 4; ++j)
            mx[j] = fmaxf(fmaxf(s[0][j], s[1][j]), fmaxf(s[2][j], s[3][j]));
        #pragma unroll
        for (int d = 1; d < 16; d <<= 1)
            #pragma unroll
            for (int j = 0; j < 4; ++j) mx[j] = fmaxf(mx[j], __shfl_xor(mx[j], d));

        float corr[4], sum[4];
        #pragma unroll
        for (int j = 0; j < 4; ++j) {
            float mn = fmaxf(m[j], mx[j]);
            corr[j] = __expf(m[j] - mn);
            m[j] = mn; sum[j] = 0.f;
        }
        #pragma unroll
        for (int n = 0; n < 4; ++n)
            #pragma unroll
            for (int j = 0; j < 4; ++j) {
                float p = __expf(s[n][j] - m[j]);
                s[n][j] = p; sum[j] += p;
            }
        #pragma unroll
        for (int d = 1; d < 16; d <<= 1)
            #pragma unroll
            for (int j = 0; j < 4; ++j) sum[j] += __shfl_xor(sum[j], d);
        #pragma unroll
        for (int j = 0; j < 4; ++j) l[j] = l[j] * corr[j] + sum[j];
        #pragma unroll
        for (int hf = 0; hf < 4; ++hf)
            #pragma unroll
            for (int j = 0; j < 4; ++j) o[hf][j] *= corr[j];

        // ---- P -> per-wave LDS (bf16, 16B-chunk XOR swizzle) ----
        #pragma unroll
        for (int n = 0; n < 4; ++n)
            #pragma unroll
            for (int j = 0; j < 4; ++j) {
                int qq = hi4 * 4 + j, kk = n * 16 + fr;
                P[qq * 64 + (((kk >> 3) ^ (qq & 7)) << 3) + (kk & 7)] = f2bf(s[n][j]);
            }

        // ---- PV: A = P (from LDS), B = Vt (global) ----
        s16x8 pa0 = *(const s16x8*)&P[fr * 64 + ((hi4 ^ (fr & 7)) << 3)];
        s16x8 pa1 = *(const s16x8*)&P[fr * 64 + (((4 + hi4) ^ (fr & 7)) << 3)];
        #pragma unroll
        for (int hf = 0; hf < 4; ++hf) {
            const unsigned short* vr = &vp[(size_t)(hf * 16 + fr) * T_ + kt0 + hi4 * 8];
            s16x8 vf0 = *(const s16x8*)vr;
            s16x8 vf1 = *(const s16x8*)(vr + 32);
            o[hf] = __builtin_amdgcn_mfma_f32_16x16x32_bf16(pa0, vf0, o[hf], 0, 0, 0);
            o[hf] = __builtin_amdgcn_mfma_f32_16x16x32_bf16(pa1, vf1, o[hf], 0, 0, 0);
        }
    }

    // ---- write per-wave partials, combine ----
    if (fr == 0) {
        #pragma unroll
        for (int j = 0; j < 4; ++j) {
            Mm[w][hi4 * 4 + j] = m[j];
            Ll[w][hi4 * 4 + j] = l[j];
        }
    }
    #pragma unroll
    for (int hf = 0; hf < 4; ++hf)
        #pragma unroll
        for (int j = 0; j < 4; ++j)
            Os[w][hi4 * 4 + j][hf * 16 + fr] = o[hf][j];
    __syncthreads();

    if (t < 256) {
        int qq = t >> 4, h0 = (t & 15) * 4;
        float M = NEG_;
        #pragma unroll
        for (int s8 = 0; s8 < 8; ++s8) M = fmaxf(M, Mm[s8][qq]);
        float L = 0.f;
        f32x4 r = (f32x4){0.f, 0.f, 0.f, 0.f};
        #pragma unroll
        for (int s8 = 0; s8 < 8; ++s8) {
            float e = __expf(Mm[s8][qq] - M);
            L += Ll[s8][qq] * e;
            f32x4 osv = *(const f32x4*)&Os[s8][qq][h0];
            r.x = fmaf(osv.x, e, r.x);
            r.y = fmaf(osv.y, e, r.y);
            r.z = fmaf(osv.z, e, r.z);
            r.w = fmaf(osv.w, e, r.w);
        }
        float il = 1.0f / L;
        r.x *= il; r.y *= il; r.z *= il; r.w *= il;
        *(f32x4*)&out[((size_t)b * T_ + qbase + qq) * H_ + h0] = r;
    }
}

extern "C" void kernel_launch(void* const* d_in, const int* in_sizes, int n_in,
                              void* d_out, int out_size, void* d_ws, size_t ws_size,
                              hipStream_t stream) {
    const float* x  = (const float*)d_in[0];
    const float* Wq = (const float*)d_in[1];
    const float* Wk = (const float*)d_in[2];
    const float* Wv = (const float*)d_in[3];
    float* outp = (float*)d_out;

    unsigned short* base = (unsigned short*)d_ws;
    unsigned short* qbw = base;
    unsigned short* kbw = base + 524288;
    unsigned short* vtw = base + 1048576;

    proj_mfma<<<(B_ * T_ / 64) * 3, 256, 0, stream>>>(x, Wq, Wk, Wv, qbw, kbw, vtw);
    attn_mfma<<<B_ * (T_ / 16), 512, 0, stream>>>(qbw, kbw, vtw, outp);
}

// Round 4
// 49.570 us; speedup vs baseline: 10.6989x; 1.0105x over previous
//
#include <hip/hip_runtime.h>
#include <cmath>

#define B_ 4
#define T_ 2048
#define C_ 1024
#define H_ 64
#define SCALE_ 0.03125f   /* 1024^-0.5 */
#define NEG_ -3.0e38f

typedef __attribute__((ext_vector_type(4))) float f32x4;
typedef __attribute__((ext_vector_type(8))) short s16x8;
typedef __attribute__((ext_vector_type(4))) unsigned short u16x4;

__device__ inline unsigned short f2bf(float f) {
    union { float f; unsigned u; } v; v.f = f;
    unsigned r = v.u + 0x7FFFu + ((v.u >> 16) & 1u);
    return (unsigned short)(r >> 16);
}

#define LDK 72  /* padded k-stride in bf16 elems */

// ---------------- projection via bf16 MFMA (unchanged from R3) ----------------
__global__ __launch_bounds__(256) void proj_mfma(
    const float* __restrict__ x, const float* __restrict__ Wq,
    const float* __restrict__ Wk, const float* __restrict__ Wv,
    unsigned short* __restrict__ qb, unsigned short* __restrict__ kb,
    unsigned short* __restrict__ vt)
{
    __shared__ unsigned short As[64 * LDK];   // [row][k]; reused as transpose buf
    __shared__ unsigned short Bs[64 * LDK];   // [col][k]  (W transposed)

    const int t = threadIdx.x;
    const int lane = t & 63;
    const int w = t >> 6;
    const int blk = blockIdx.x;
    const int mat = blk % 3;
    const int row0 = (blk / 3) * 64;

    const float* W = (mat == 0) ? Wq : (mat == 1) ? Wk : Wv;

    const int wr = (w >> 1) * 32;
    const int wc = (w & 1) * 32;
    const int fr = lane & 15;
    const int ko = (lane >> 4) * 8;

    f32x4 acc[2][2];
    #pragma unroll
    for (int mi = 0; mi < 2; ++mi)
        #pragma unroll
        for (int ni = 0; ni < 2; ++ni)
            acc[mi][ni] = (f32x4){0.f, 0.f, 0.f, 0.f};

    const int bcol = t & 63;
    const int bkg  = (t >> 6) * 4;

    for (int kt = 0; kt < C_; kt += 64) {
        __syncthreads();
        #pragma unroll
        for (int i = 0; i < 4; ++i) {
            int idx = t + i * 256;
            int r = idx >> 4, kc = (idx & 15) * 4;
            f32x4 xv = *(const f32x4*)(x + (size_t)(row0 + r) * C_ + kt + kc);
            u16x4 bv;
            bv.x = f2bf(xv.x); bv.y = f2bf(xv.y); bv.z = f2bf(xv.z); bv.w = f2bf(xv.w);
            *(u16x4*)&As[r * LDK + kc] = bv;
        }
        #pragma unroll
        for (int i = 0; i < 4; ++i) {
            int kk0 = bkg + i * 16;
            u16x4 bv;
            bv.x = f2bf(W[(size_t)(kt + kk0 + 0) * H_ + bcol]);
            bv.y = f2bf(W[(size_t)(kt + kk0 + 1) * H_ + bcol]);
            bv.z = f2bf(W[(size_t)(kt + kk0 + 2) * H_ + bcol]);
            bv.w = f2bf(W[(size_t)(kt + kk0 + 3) * H_ + bcol]);
            *(u16x4*)&Bs[bcol * LDK + kk0] = bv;
        }
        __syncthreads();
        #pragma unroll
        for (int ks = 0; ks < 2; ++ks) {
            s16x8 a0 = *(const s16x8*)&As[(wr + fr) * LDK + ks * 32 + ko];
            s16x8 a1 = *(const s16x8*)&As[(wr + 16 + fr) * LDK + ks * 32 + ko];
            s16x8 b0 = *(const s16x8*)&Bs[(wc + fr) * LDK + ks * 32 + ko];
            s16x8 b1 = *(const s16x8*)&Bs[(wc + 16 + fr) * LDK + ks * 32 + ko];
            acc[0][0] = __builtin_amdgcn_mfma_f32_16x16x32_bf16(a0, b0, acc[0][0], 0, 0, 0);
            acc[0][1] = __builtin_amdgcn_mfma_f32_16x16x32_bf16(a0, b1, acc[0][1], 0, 0, 0);
            acc[1][0] = __builtin_amdgcn_mfma_f32_16x16x32_bf16(a1, b0, acc[1][0], 0, 0, 0);
            acc[1][1] = __builtin_amdgcn_mfma_f32_16x16x32_bf16(a1, b1, acc[1][1], 0, 0, 0);
        }
    }

    // C/D layout: col = lane&15, row = (lane>>4)*4 + reg
    if (mat < 2) {
        unsigned short* outb = (mat == 0) ? qb : kb;
        #pragma unroll
        for (int mi = 0; mi < 2; ++mi)
            #pragma unroll
            for (int ni = 0; ni < 2; ++ni)
                #pragma unroll
                for (int j = 0; j < 4; ++j) {
                    int row = row0 + wr + mi * 16 + (lane >> 4) * 4 + j;
                    int col = wc + ni * 16 + fr;
                    outb[(size_t)row * H_ + col] = f2bf(acc[mi][ni][j]);
                }
    } else {
        // transpose V tile through LDS -> vt[b][h][t] coalesced
        __syncthreads();
        #pragma unroll
        for (int mi = 0; mi < 2; ++mi)
            #pragma unroll
            for (int ni = 0; ni < 2; ++ni)
                #pragma unroll
                for (int j = 0; j < 4; ++j) {
                    int r = wr + mi * 16 + (lane >> 4) * 4 + j;   // local key row
                    int cc = wc + ni * 16 + fr;                   // h
                    As[cc * LDK + r] = f2bf(acc[mi][ni][j]);
                }
        __syncthreads();
        int h = t >> 2, c0 = (t & 3) * 16;
        int bb = row0 >> 11, trow = row0 & 2047;
        s16x8 v0 = *(const s16x8*)&As[h * LDK + c0];
        s16x8 v1 = *(const s16x8*)&As[h * LDK + c0 + 8];
        size_t dst = (size_t)bb * H_ * T_ + (size_t)h * T_ + trow + c0;
        *(s16x8*)&vt[dst] = v0;
        *(s16x8*)&vt[dst + 8] = v1;
    }
}

// ---------------- MFMA flash attention, 8-way key-split, swapped QK^T ----------------
// mfma(K,Q) -> D[row=key][col=q]: each lane owns ONE q-row (fr) and 16 keys.
// Row reduce = local 16-val VALU chain + 2 shfl_xor (was 4+4 steps). m,l scalar.
__global__ __launch_bounds__(512, 4) void attn_mfma(
    const unsigned short* __restrict__ qb, const unsigned short* __restrict__ kb,
    const unsigned short* __restrict__ vt, float* __restrict__ out)
{
    __shared__ alignas(16) unsigned short Ps[8][1024];  // per-wave P (swizzled)
    __shared__ float Os[8][16][68];
    __shared__ float Mm[8][16];
    __shared__ float Ll[8][16];

    const int t = threadIdx.x, lane = t & 63, w = t >> 6;
    const int fr = lane & 15, hi4 = lane >> 4;
    const int blk = blockIdx.x;
    const int b = blk & 3;
    const int qt = 127 - (blk >> 2);     // big q-tiles dispatch first
    const int qbase = qt * 16;

    const unsigned short* qp = qb + ((size_t)b * T_ + qbase) * H_;
    const unsigned short* kp = kb + (size_t)b * T_ * H_;
    const unsigned short* vp = vt + (size_t)b * H_ * T_;

    // Q frag: lane supplies Q[q=fr][k=8*hi4..+7] — serves as B-operand of mfma(K,Q)
    s16x8 qf0 = *(const s16x8*)&qp[fr * H_ + hi4 * 8];
    s16x8 qf1 = *(const s16x8*)&qp[fr * H_ + 32 + hi4 * 8];

    const int nt = (qbase + 79) >> 6;    // tiles covering keys 0..qbase+15
    const int per = (nt + 7) >> 3;
    const int tb = w * per;
    int te = tb + per; if (te > nt) te = nt;

    float m = NEG_, l = 0.f;
    f32x4 o[4];
    #pragma unroll
    for (int hf = 0; hf < 4; ++hf) o[hf] = (f32x4){0.f, 0.f, 0.f, 0.f};

    unsigned short* P = &Ps[w][0];
    const int swz = (fr & 3) << 4;
    const int qrow = qbase + fr;

    for (int kt = tb; kt < te; ++kt) {
        const int kt0 = kt << 6;

        // ---- QK^T swapped: D[row=key][col=q] ----
        f32x4 s[4];
        #pragma unroll
        for (int n = 0; n < 4; ++n) {
            const unsigned short* kr = &kp[(size_t)(kt0 + n * 16 + fr) * H_ + hi4 * 8];
            s16x8 kf0 = *(const s16x8*)kr;
            s16x8 kf1 = *(const s16x8*)(kr + 32);
            f32x4 a = (f32x4){0.f, 0.f, 0.f, 0.f};
            a = __builtin_amdgcn_mfma_f32_16x16x32_bf16(kf0, qf0, a, 0, 0, 0);
            a = __builtin_amdgcn_mfma_f32_16x16x32_bf16(kf1, qf1, a, 0, 0, 0);
            s[n] = a;
        }

        // ---- scale + causal mask (all 16 vals belong to q-row = fr) ----
        if (kt0 + 63 > qbase) {
            #pragma unroll
            for (int n = 0; n < 4; ++n)
                #pragma unroll
                for (int j = 0; j < 4; ++j) {
                    int key = kt0 + n * 16 + hi4 * 4 + j;
                    float sv = s[n][j] * SCALE_;
                    s[n][j] = (key > qrow) ? NEG_ : sv;
                }
        } else {
            #pragma unroll
            for (int n = 0; n < 4; ++n)
                #pragma unroll
                for (int j = 0; j < 4; ++j) s[n][j] *= SCALE_;
        }

        // ---- row reduce: local 16-max + 2 shfl steps ----
        float mx01 = fmaxf(fmaxf(s[0][0], s[0][1]), fmaxf(s[0][2], s[0][3]));
        float mx23 = fmaxf(fmaxf(s[1][0], s[1][1]), fmaxf(s[1][2], s[1][3]));
        float mx45 = fmaxf(fmaxf(s[2][0], s[2][1]), fmaxf(s[2][2], s[2][3]));
        float mx67 = fmaxf(fmaxf(s[3][0], s[3][1]), fmaxf(s[3][2], s[3][3]));
        float mx = fmaxf(fmaxf(mx01, mx23), fmaxf(mx45, mx67));
        mx = fmaxf(mx, __shfl_xor(mx, 16));
        mx = fmaxf(mx, __shfl_xor(mx, 32));

        float mn = fmaxf(m, mx);
        float corr = __expf(m - mn);
        m = mn;
        float sum = 0.f;
        #pragma unroll
        for (int n = 0; n < 4; ++n)
            #pragma unroll
            for (int j = 0; j < 4; ++j) {
                float p = __expf(s[n][j] - mn);
                s[n][j] = p; sum += p;
            }
        sum += __shfl_xor(sum, 16);
        sum += __shfl_xor(sum, 32);
        l = l * corr + sum;

        // ---- rescale O with row-matched corr (O rows = hi4*4+j) ----
        #pragma unroll
        for (int j = 0; j < 4; ++j) {
            float cj = __shfl(corr, (lane & 48) + hi4 * 4 + j);
            o[0][j] *= cj; o[1][j] *= cj; o[2][j] *= cj; o[3][j] *= cj;
        }

        // ---- P -> per-wave LDS: 4x u16x4 writes, XOR-swizzled ----
        #pragma unroll
        for (int n = 0; n < 4; ++n) {
            u16x4 pk;
            pk.x = f2bf(s[n][0]); pk.y = f2bf(s[n][1]);
            pk.z = f2bf(s[n][2]); pk.w = f2bf(s[n][3]);
            *(u16x4*)&P[fr * 64 + ((n * 16 + hi4 * 4) ^ swz)] = pk;
        }
        s16x8 pa0 = *(const s16x8*)&P[fr * 64 + ((hi4 * 8) ^ swz)];
        s16x8 pa1 = *(const s16x8*)&P[fr * 64 + ((32 + hi4 * 8) ^ swz)];

        // ---- PV: A = P, B = Vt (global) ----
        #pragma unroll
        for (int hf = 0; hf < 4; ++hf) {
            const unsigned short* vr = &vp[(size_t)(hf * 16 + fr) * T_ + kt0 + hi4 * 8];
            s16x8 vf0 = *(const s16x8*)vr;
            s16x8 vf1 = *(const s16x8*)(vr + 32);
            o[hf] = __builtin_amdgcn_mfma_f32_16x16x32_bf16(pa0, vf0, o[hf], 0, 0, 0);
            o[hf] = __builtin_amdgcn_mfma_f32_16x16x32_bf16(pa1, vf1, o[hf], 0, 0, 0);
        }
    }

    // ---- write per-wave partials, combine ----
    if (hi4 == 0) { Mm[w][fr] = m; Ll[w][fr] = l; }
    #pragma unroll
    for (int hf = 0; hf < 4; ++hf)
        #pragma unroll
        for (int j = 0; j < 4; ++j)
            Os[w][hi4 * 4 + j][hf * 16 + fr] = o[hf][j];
    __syncthreads();

    if (t < 256) {
        int qq = t >> 4, h0 = (t & 15) * 4;
        float M = NEG_;
        #pragma unroll
        for (int s8 = 0; s8 < 8; ++s8) M = fmaxf(M, Mm[s8][qq]);
        float L = 0.f;
        f32x4 r = (f32x4){0.f, 0.f, 0.f, 0.f};
        #pragma unroll
        for (int s8 = 0; s8 < 8; ++s8) {
            float e = __expf(Mm[s8][qq] - M);
            L += Ll[s8][qq] * e;
            f32x4 osv = *(const f32x4*)&Os[s8][qq][h0];
            r.x = fmaf(osv.x, e, r.x);
            r.y = fmaf(osv.y, e, r.y);
            r.z = fmaf(osv.z, e, r.z);
            r.w = fmaf(osv.w, e, r.w);
        }
        float il = 1.0f / L;
        r.x *= il; r.y *= il; r.z *= il; r.w *= il;
        *(f32x4*)&out[((size_t)b * T_ + qbase + qq) * H_ + h0] = r;
    }
}

extern "C" void kernel_launch(void* const* d_in, const int* in_sizes, int n_in,
                              void* d_out, int out_size, void* d_ws, size_t ws_size,
                              hipStream_t stream) {
    const float* x  = (const float*)d_in[0];
    const float* Wq = (const float*)d_in[1];
    const float* Wk = (const float*)d_in[2];
    const float* Wv = (const float*)d_in[3];
    float* outp = (float*)d_out;

    unsigned short* base = (unsigned short*)d_ws;
    unsigned short* qbw = base;
    unsigned short* kbw = base + 524288;
    unsigned short* vtw = base + 1048576;

    proj_mfma<<<(B_ * T_ / 64) * 3, 256, 0, stream>>>(x, Wq, Wk, Wv, qbw, kbw, vtw);
    attn_mfma<<<B_ * (T_ / 16), 512, 0, stream>>>(qbw, kbw, vtw, outp);
}

// Round 5
// 48.512 us; speedup vs baseline: 10.9321x; 1.0218x over previous
//
#include <hip/hip_runtime.h>
#include <hip/hip_bf16.h>
#include <cmath>

#define B_ 4
#define T_ 2048
#define C_ 1024
#define H_ 64
#define SCALE_ 0.03125f          /* 1024^-0.5 */
#define K2_ 0.04508422003f       /* SCALE_ * log2(e) */
#define THRRAW_ 177.0f           /* defer-max threshold: 8 / K2_ */
#define NEG_ -3.0e38f

typedef __attribute__((ext_vector_type(4))) float f32x4;
typedef __attribute__((ext_vector_type(8))) short s16x8;
typedef __attribute__((ext_vector_type(4))) unsigned short u16x4;

__device__ inline unsigned short f2bf(float f) {
    union { __hip_bfloat16 h; unsigned short u; } cv;
    cv.h = __float2bfloat16(f);   // compiler fuses pairs into v_cvt_pk_bf16_f32
    return cv.u;
}

#define LDK 72  /* padded k-stride in bf16 elems */

// ---------------- projection via bf16 MFMA ----------------
__global__ __launch_bounds__(256) void proj_mfma(
    const float* __restrict__ x, const float* __restrict__ Wq,
    const float* __restrict__ Wk, const float* __restrict__ Wv,
    unsigned short* __restrict__ qb, unsigned short* __restrict__ kb,
    unsigned short* __restrict__ vt)
{
    __shared__ unsigned short As[64 * LDK];   // [row][k]; reused as transpose buf
    __shared__ unsigned short Bs[64 * LDK];   // [col][k]  (W transposed)

    const int t = threadIdx.x;
    const int lane = t & 63;
    const int w = t >> 6;
    const int blk = blockIdx.x;
    const int mat = blk % 3;
    const int row0 = (blk / 3) * 64;

    const float* W = (mat == 0) ? Wq : (mat == 1) ? Wk : Wv;

    const int wr = (w >> 1) * 32;
    const int wc = (w & 1) * 32;
    const int fr = lane & 15;
    const int ko = (lane >> 4) * 8;

    f32x4 acc[2][2];
    #pragma unroll
    for (int mi = 0; mi < 2; ++mi)
        #pragma unroll
        for (int ni = 0; ni < 2; ++ni)
            acc[mi][ni] = (f32x4){0.f, 0.f, 0.f, 0.f};

    const int bcol = t & 63;
    const int bkg  = (t >> 6) * 4;

    for (int kt = 0; kt < C_; kt += 64) {
        __syncthreads();
        #pragma unroll
        for (int i = 0; i < 4; ++i) {
            int idx = t + i * 256;
            int r = idx >> 4, kc = (idx & 15) * 4;
            f32x4 xv = *(const f32x4*)(x + (size_t)(row0 + r) * C_ + kt + kc);
            u16x4 bv;
            bv.x = f2bf(xv.x); bv.y = f2bf(xv.y); bv.z = f2bf(xv.z); bv.w = f2bf(xv.w);
            *(u16x4*)&As[r * LDK + kc] = bv;
        }
        #pragma unroll
        for (int i = 0; i < 4; ++i) {
            int kk0 = bkg + i * 16;
            u16x4 bv;
            bv.x = f2bf(W[(size_t)(kt + kk0 + 0) * H_ + bcol]);
            bv.y = f2bf(W[(size_t)(kt + kk0 + 1) * H_ + bcol]);
            bv.z = f2bf(W[(size_t)(kt + kk0 + 2) * H_ + bcol]);
            bv.w = f2bf(W[(size_t)(kt + kk0 + 3) * H_ + bcol]);
            *(u16x4*)&Bs[bcol * LDK + kk0] = bv;
        }
        __syncthreads();
        #pragma unroll
        for (int ks = 0; ks < 2; ++ks) {
            s16x8 a0 = *(const s16x8*)&As[(wr + fr) * LDK + ks * 32 + ko];
            s16x8 a1 = *(const s16x8*)&As[(wr + 16 + fr) * LDK + ks * 32 + ko];
            s16x8 b0 = *(const s16x8*)&Bs[(wc + fr) * LDK + ks * 32 + ko];
            s16x8 b1 = *(const s16x8*)&Bs[(wc + 16 + fr) * LDK + ks * 32 + ko];
            acc[0][0] = __builtin_amdgcn_mfma_f32_16x16x32_bf16(a0, b0, acc[0][0], 0, 0, 0);
            acc[0][1] = __builtin_amdgcn_mfma_f32_16x16x32_bf16(a0, b1, acc[0][1], 0, 0, 0);
            acc[1][0] = __builtin_amdgcn_mfma_f32_16x16x32_bf16(a1, b0, acc[1][0], 0, 0, 0);
            acc[1][1] = __builtin_amdgcn_mfma_f32_16x16x32_bf16(a1, b1, acc[1][1], 0, 0, 0);
        }
    }

    // C/D layout: col = lane&15, row = (lane>>4)*4 + reg
    if (mat < 2) {
        unsigned short* outb = (mat == 0) ? qb : kb;
        #pragma unroll
        for (int mi = 0; mi < 2; ++mi)
            #pragma unroll
            for (int ni = 0; ni < 2; ++ni)
                #pragma unroll
                for (int j = 0; j < 4; ++j) {
                    int row = row0 + wr + mi * 16 + (lane >> 4) * 4 + j;
                    int col = wc + ni * 16 + fr;
                    outb[(size_t)row * H_ + col] = f2bf(acc[mi][ni][j]);
                }
    } else {
        // transpose V tile through LDS -> vt[b][h][t] coalesced
        __syncthreads();
        #pragma unroll
        for (int mi = 0; mi < 2; ++mi)
            #pragma unroll
            for (int ni = 0; ni < 2; ++ni)
                #pragma unroll
                for (int j = 0; j < 4; ++j) {
                    int r = wr + mi * 16 + (lane >> 4) * 4 + j;   // local key row
                    int cc = wc + ni * 16 + fr;                   // h
                    As[cc * LDK + r] = f2bf(acc[mi][ni][j]);
                }
        __syncthreads();
        int h = t >> 2, c0 = (t & 3) * 16;
        int bb = row0 >> 11, trow = row0 & 2047;
        s16x8 v0 = *(const s16x8*)&As[h * LDK + c0];
        s16x8 v1 = *(const s16x8*)&As[h * LDK + c0 + 8];
        size_t dst = (size_t)bb * H_ * T_ + (size_t)h * T_ + trow + c0;
        *(s16x8*)&vt[dst] = v0;
        *(s16x8*)&vt[dst + 8] = v1;
    }
}

// ---------------- MFMA flash attention, 8-way key-split, swapped QK^T ----------------
// Raw-score domain throughout; scale folded into exp2 (P = 2^((s-m)*K2)).
// Defer-max (T13): steady-state tiles skip row-max shuffles + O rescale.
__global__ __launch_bounds__(512, 4) void attn_mfma(
    const unsigned short* __restrict__ qb, const unsigned short* __restrict__ kb,
    const unsigned short* __restrict__ vt, float* __restrict__ out)
{
    __shared__ alignas(16) unsigned short Ps[8][1024];  // per-wave P (swizzled)
    __shared__ float Os[8][16][68];
    __shared__ float Mm[8][16];
    __shared__ float Ll[8][16];

    const int t = threadIdx.x, lane = t & 63, w = t >> 6;
    const int fr = lane & 15, hi4 = lane >> 4;
    const int blk = blockIdx.x;
    const int b = blk & 3;
    const int qt = 127 - (blk >> 2);     // big q-tiles dispatch first
    const int qbase = qt * 16;

    const unsigned short* qp = qb + ((size_t)b * T_ + qbase) * H_;
    const unsigned short* kp = kb + (size_t)b * T_ * H_;
    const unsigned short* vp = vt + (size_t)b * H_ * T_;

    // Q frag: lane supplies Q[q=fr][k=8*hi4..+7] — B-operand of mfma(K,Q)
    s16x8 qf0 = *(const s16x8*)&qp[fr * H_ + hi4 * 8];
    s16x8 qf1 = *(const s16x8*)&qp[fr * H_ + 32 + hi4 * 8];

    const int nt = (qbase + 79) >> 6;    // tiles covering keys 0..qbase+15
    const int per = (nt + 7) >> 3;
    const int tb = w * per;
    int te = tb + per; if (te > nt) te = nt;

    float m = NEG_, l = 0.f;
    f32x4 o[4];
    #pragma unroll
    for (int hf = 0; hf < 4; ++hf) o[hf] = (f32x4){0.f, 0.f, 0.f, 0.f};

    unsigned short* P = &Ps[w][0];
    const int swz = (fr & 3) << 4;
    const int qrow = qbase + fr;

    for (int kt = tb; kt < te; ++kt) {
        const int kt0 = kt << 6;

        // ---- QK^T swapped: D[row=key][col=q]; lane owns q-row fr, 16 keys ----
        f32x4 s[4];
        #pragma unroll
        for (int n = 0; n < 4; ++n) {
            const unsigned short* kr = &kp[(size_t)(kt0 + n * 16 + fr) * H_ + hi4 * 8];
            s16x8 kf0 = *(const s16x8*)kr;
            s16x8 kf1 = *(const s16x8*)(kr + 32);
            f32x4 a = (f32x4){0.f, 0.f, 0.f, 0.f};
            a = __builtin_amdgcn_mfma_f32_16x16x32_bf16(kf0, qf0, a, 0, 0, 0);
            a = __builtin_amdgcn_mfma_f32_16x16x32_bf16(kf1, qf1, a, 0, 0, 0);
            s[n] = a;
        }

        // ---- issue V loads now; consumed after softmax (latency hidden) ----
        s16x8 vf[4][2];
        #pragma unroll
        for (int hf = 0; hf < 4; ++hf) {
            const unsigned short* vr = &vp[(size_t)(hf * 16 + fr) * T_ + kt0 + hi4 * 8];
            vf[hf][0] = *(const s16x8*)vr;
            vf[hf][1] = *(const s16x8*)(vr + 32);
        }

        // ---- causal mask in raw domain (boundary tiles only; kt0 <= qbase) ----
        if (kt0 + 63 > qbase) {
            #pragma unroll
            for (int n = 0; n < 4; ++n)
                #pragma unroll
                for (int j = 0; j < 4; ++j) {
                    int key = kt0 + n * 16 + hi4 * 4 + j;
                    s[n][j] = (key > qrow) ? NEG_ : s[n][j];
                }
        }

        // ---- defer-max online softmax ----
        float mxl = fmaxf(fmaxf(fmaxf(fmaxf(s[0][0], s[0][1]), fmaxf(s[0][2], s[0][3])),
                                fmaxf(fmaxf(s[1][0], s[1][1]), fmaxf(s[1][2], s[1][3]))),
                          fmaxf(fmaxf(fmaxf(s[2][0], s[2][1]), fmaxf(s[2][2], s[2][3])),
                                fmaxf(fmaxf(s[3][0], s[3][1]), fmaxf(s[3][2], s[3][3]))));
        if (!__all(mxl - m <= THRRAW_)) {
            float mx = fmaxf(mxl, __shfl_xor(mxl, 16));
            mx = fmaxf(mx, __shfl_xor(mx, 32));
            float mn = fmaxf(m, mx);
            float corr = exp2f((m - mn) * K2_);
            m = mn;
            l *= corr;
            #pragma unroll
            for (int j = 0; j < 4; ++j) {
                float cj = __shfl(corr, (lane & 48) + hi4 * 4 + j);
                o[0][j] *= cj; o[1][j] *= cj; o[2][j] *= cj; o[3][j] *= cj;
            }
        }
        const float nmk = -m * K2_;
        float sum = 0.f;
        #pragma unroll
        for (int n = 0; n < 4; ++n)
            #pragma unroll
            for (int j = 0; j < 4; ++j) {
                float p = exp2f(fmaf(s[n][j], K2_, nmk));
                s[n][j] = p; sum += p;
            }
        sum += __shfl_xor(sum, 16);
        sum += __shfl_xor(sum, 32);
        l += sum;

        // ---- P -> per-wave LDS: 4x u16x4 writes, XOR-swizzled ----
        #pragma unroll
        for (int n = 0; n < 4; ++n) {
            u16x4 pk;
            pk.x = f2bf(s[n][0]); pk.y = f2bf(s[n][1]);
            pk.z = f2bf(s[n][2]); pk.w = f2bf(s[n][3]);
            *(u16x4*)&P[fr * 64 + ((n * 16 + hi4 * 4) ^ swz)] = pk;
        }
        s16x8 pa0 = *(const s16x8*)&P[fr * 64 + ((hi4 * 8) ^ swz)];
        s16x8 pa1 = *(const s16x8*)&P[fr * 64 + ((32 + hi4 * 8) ^ swz)];

        // ---- PV: A = P, B = Vt (preloaded) ----
        #pragma unroll
        for (int hf = 0; hf < 4; ++hf) {
            o[hf] = __builtin_amdgcn_mfma_f32_16x16x32_bf16(pa0, vf[hf][0], o[hf], 0, 0, 0);
            o[hf] = __builtin_amdgcn_mfma_f32_16x16x32_bf16(pa1, vf[hf][1], o[hf], 0, 0, 0);
        }
    }

    // ---- write per-wave partials, combine ----
    if (hi4 == 0) { Mm[w][fr] = m; Ll[w][fr] = l; }
    #pragma unroll
    for (int hf = 0; hf < 4; ++hf)
        #pragma unroll
        for (int j = 0; j < 4; ++j)
            Os[w][hi4 * 4 + j][hf * 16 + fr] = o[hf][j];
    __syncthreads();

    if (t < 256) {
        int qq = t >> 4, h0 = (t & 15) * 4;
        float M = NEG_;
        #pragma unroll
        for (int s8 = 0; s8 < 8; ++s8) M = fmaxf(M, Mm[s8][qq]);
        float L = 0.f;
        f32x4 r = (f32x4){0.f, 0.f, 0.f, 0.f};
        #pragma unroll
        for (int s8 = 0; s8 < 8; ++s8) {
            float e = exp2f((Mm[s8][qq] - M) * K2_);   // raw-domain partials
            L += Ll[s8][qq] * e;
            f32x4 osv = *(const f32x4*)&Os[s8][qq][h0];
            r.x = fmaf(osv.x, e, r.x);
            r.y = fmaf(osv.y, e, r.y);
            r.z = fmaf(osv.z, e, r.z);
            r.w = fmaf(osv.w, e, r.w);
        }
        float il = 1.0f / L;
        r.x *= il; r.y *= il; r.z *= il; r.w *= il;
        *(f32x4*)&out[((size_t)b * T_ + qbase + qq) * H_ + h0] = r;
    }
}

extern "C" void kernel_launch(void* const* d_in, const int* in_sizes, int n_in,
                              void* d_out, int out_size, void* d_ws, size_t ws_size,
                              hipStream_t stream) {
    const float* x  = (const float*)d_in[0];
    const float* Wq = (const float*)d_in[1];
    const float* Wk = (const float*)d_in[2];
    const float* Wv = (const float*)d_in[3];
    float* outp = (float*)d_out;

    unsigned short* base = (unsigned short*)d_ws;
    unsigned short* qbw = base;
    unsigned short* kbw = base + 524288;
    unsigned short* vtw = base + 1048576;

    proj_mfma<<<(B_ * T_ / 64) * 3, 256, 0, stream>>>(x, Wq, Wk, Wv, qbw, kbw, vtw);
    attn_mfma<<<B_ * (T_ / 16), 512, 0, stream>>>(qbw, kbw, vtw, outp);
}